// Round 4
// baseline (1080.502 us; speedup 1.0000x reference)
//
#include <hip/hip_runtime.h>
#include <math.h>

#define N_ROWS 65536
#define CB 1024
#define SPLITS 4
#define JS (CB / SPLITS)   // 256 codebook entries per split

typedef float v4f __attribute__((ext_vector_type(4)));

// ---------------------------------------------------------------------------
// Exact emulation of numpy's pairwise_sum for n=64 fp32 (AVX-512 path):
//   r0..r3 = 16-lane vector loads; sum = (r0+r1)+(r2+r3);
//   then _mm512_reduce_add_ps tree: fold at lane distance 8, 4, 2, 1.
// fp contract OFF so the squares are not fused into the adds.
// ---------------------------------------------------------------------------
__device__ __forceinline__ float tree_sum64_sq(const float* x) {
#pragma clang fp contract(off)
    float sq[64];
#pragma unroll
    for (int i = 0; i < 64; ++i) sq[i] = x[i] * x[i];
    float s[16];
#pragma unroll
    for (int l = 0; l < 16; ++l) s[l] = (sq[l] + sq[l + 16]) + (sq[l + 32] + sq[l + 48]);
    float t[8];
#pragma unroll
    for (int l = 0; l < 8; ++l) t[l] = s[l] + s[l + 8];
    float u[4];
#pragma unroll
    for (int l = 0; l < 4; ++l) u[l] = t[l] + t[l + 4];
    float v0 = u[0] + u[2];
    float v1 = u[1] + u[3];
    return v0 + v1;
}

// sorted-triple insert, strict < (ties keep earlier-inserted = lower index,
// matching jax.lax.top_k stable tie-breaking when fed in ascending index order)
__device__ __forceinline__ void top3_insert(float d, int j,
                                            float& v0, float& v1, float& v2,
                                            int& i0, int& i1, int& i2) {
    bool b0 = d < v0, b1 = d < v1, b2 = d < v2;
    v2 = b1 ? v1 : (b2 ? d : v2);
    i2 = b1 ? i1 : (b2 ? j : i2);
    v1 = b0 ? v0 : (b1 ? d : v1);
    i1 = b0 ? i0 : (b1 ? j : i1);
    v0 = b0 ? d : v0;
    i0 = b0 ? j : i0;
}

// ---------------------------------------------------------------------------
// B[j] = np.sum(emb[j]**2) (exact tree emulation) + zero hist/lossAcc.
// ---------------------------------------------------------------------------
__global__ __launch_bounds__(256) void prep_kernel(const float* __restrict__ emb,
                                                   float* __restrict__ B,
                                                   int* __restrict__ hist,
                                                   float* __restrict__ lossAcc) {
    int j = blockIdx.x * 256 + threadIdx.x;
    if (j >= CB) return;
    float e[64];
    const float4* e4 = (const float4*)(emb + (size_t)j * 64);
#pragma unroll
    for (int k = 0; k < 16; ++k) {
        float4 v = e4[k];
        e[4 * k] = v.x; e[4 * k + 1] = v.y; e[4 * k + 2] = v.z; e[4 * k + 3] = v.w;
    }
    B[j] = tree_sum64_sq(e);
    hist[j] = 0;
    if (j == 0) *lossAcc = 0.0f;
}

// ---------------------------------------------------------------------------
// Fully fused: score + merge + epilogue + one-hot.
//
// Lessons encoded here:
//  * `split` goes through readfirstlane so emb/B loads stay provably uniform
//    -> scalar s_load path (losing this was 4x, round 1).
//  * R3 showed block-level fusion gives ZERO overlap: all 1024 blocks (4/CU)
//    run in lockstep, so the store phase just serializes after scoring.
//    Fix: interleave the one-hot ZERO stream (data-independent!) INTO the
//    scoring j-loop — one aligned float4 zero-store per jj (192 stores vs
//    256 iterations; ~130 VALU-cycles between issues keeps vmcnt depth ~1-2,
//    no stall). The 805 MB write stream drains under the SMEM-latency-bound
//    scoring phase instead of after it.
//  * Stores are PLAIN (not nontemporal): the harness fill kernel proves the
//    non-NT full-line path does 6.2 TB/s; our NT streams measured 2.5 TB/s.
//  * The `__syncthreads()` after scoring drains vmcnt (compiler emits
//    s_waitcnt vmcnt(0) before s_barrier), so all zeros are durable before
//    wave 0 writes the <=192 "one" positions as scalar stores. HIP
//    __syncthreads also orders global accesses within the block.
// Scoring FP order, merge tie semantics, epilogue: bit-identical to R2/R3.
// ---------------------------------------------------------------------------
__global__ __launch_bounds__(256) void fused_kernel(const float* __restrict__ z,
                                                    const float* __restrict__ emb,
                                                    const float* __restrict__ B,
                                                    float* __restrict__ out0,
                                                    float* __restrict__ out3f,
                                                    float* __restrict__ out4,
                                                    int* __restrict__ hist,
                                                    float* __restrict__ lossAcc) {
    __shared__ float sD[SPLITS][64][3];
    __shared__ int   sI[SPLITS][64][3];

    int t = threadIdx.x;
    int r = t & 63;
    int split = __builtin_amdgcn_readfirstlane(t >> 6);   // uniform -> scalar loads
    int row = blockIdx.x * 64 + r;

    // this block's contiguous one-hot region: 192 slices = 196608 floats,
    // start is always == 8 mod 16 B (out3 base elem 4194306 == 2 mod 4)
    float* Rb = out3f + (size_t)blockIdx.x * 196608;
    v4f* R4 = (v4f*)(Rb + 2);                 // 16B-aligned body: 49151 float4s
    if (t == 0) {                             // head + tail scalars, issued early
        Rb[0] = 0.0f; Rb[1] = 0.0f;
        Rb[196606] = 0.0f; Rb[196607] = 0.0f;
    }
    v4f zero4 = {0.0f, 0.0f, 0.0f, 0.0f};

    float zr[64];
    const float4* z4 = (const float4*)(z + (size_t)row * 64);
#pragma unroll
    for (int k = 0; k < 16; ++k) {
        float4 v = z4[k];
        zr[4 * k] = v.x; zr[4 * k + 1] = v.y; zr[4 * k + 2] = v.z; zr[4 * k + 3] = v.w;
    }
    float A = tree_sum64_sq(zr);

    float v0 = 3.402823466e38f, v1 = 3.402823466e38f, v2 = 3.402823466e38f;
    int i0 = 0, i1 = 0, i2 = 0;
    int jbase = split * JS;

#pragma unroll 2
    for (int jj = 0; jj < JS; ++jj) {
        // ---- interleaved one-hot zero stream (independent of scoring) ----
        if (jj < 192) {
            int m = jj * 256 + t;             // consecutive lanes -> consecutive 16B
            if (m < 49151) R4[m] = zero4;     // plain store, drains under compute
        }
        // ---- scoring (unchanged) ----
        int j = jbase + jj;                   // uniform (split is readfirstlane'd)
        const float4* e4 = (const float4*)(emb + (size_t)j * 64);
        float Bj = B[j];                      // uniform -> scalar load
        float acc = 0.0f;
#pragma unroll
        for (int k = 0; k < 16; ++k) {
            float4 e = e4[k];                 // uniform -> scalar loads
            acc = fmaf(zr[4 * k],     e.x, acc);
            acc = fmaf(zr[4 * k + 1], e.y, acc);
            acc = fmaf(zr[4 * k + 2], e.z, acc);
            acc = fmaf(zr[4 * k + 3], e.w, acc);
        }
        float d = (A + Bj) - 2.0f * acc;      // fma-contraction bit-identical
        top3_insert(d, j, v0, v1, v2, i0, i1, i2);
    }

    sD[split][r][0] = v0; sD[split][r][1] = v1; sD[split][r][2] = v2;
    sI[split][r][0] = i0; sI[split][r][1] = i1; sI[split][r][2] = i2;
    __syncthreads();                          // barrier + vmcnt drain: zeros durable

    if (t < 64) {                             // wave 0: zr holds row's z (split 0)
        float m0 = 3.402823466e38f, m1 = 3.402823466e38f, m2 = 3.402823466e38f;
        int j0 = 0, j1 = 0, j2 = 0;
#pragma unroll
        for (int s = 0; s < SPLITS; ++s) {    // ascending split = ascending index
#pragma unroll
            for (int u = 0; u < 3; ++u)
                top3_insert(sD[s][r][u], sI[s][r][u], m0, m1, m2, j0, j1, j2);
        }

        // the <=192 "one" positions, after the zeros are durable
        Rb[(r * 3    ) * 1024 + j0] = 1.0f;
        Rb[(r * 3 + 1) * 1024 + j1] = 1.0f;
        Rb[(r * 3 + 2) * 1024 + j2] = 1.0f;

        const float4* e0q = (const float4*)(emb + (size_t)j0 * 64);
        const float4* e1q = (const float4*)(emb + (size_t)j1 * 64);
        const float4* e2q = (const float4*)(emb + (size_t)j2 * 64);
        v4f* o4 = (v4f*)(out0 + (size_t)row * 64);

        float lsum = 0.0f;
#pragma unroll
        for (int k4 = 0; k4 < 16; ++k4) {
            float4 a = e0q[k4], b = e1q[k4], c = e2q[k4];   // vectorized gathers
            float zx = zr[4 * k4], zy = zr[4 * k4 + 1];
            float zz = zr[4 * k4 + 2], zw = zr[4 * k4 + 3];
            v4f st;
            float zq, df;
            zq = ((a.x + b.x) + c.x) / 3.0f; df = zq - zx; st.x = zx + df; lsum = fmaf(df, df, lsum);
            zq = ((a.y + b.y) + c.y) / 3.0f; df = zq - zy; st.y = zy + df; lsum = fmaf(df, df, lsum);
            zq = ((a.z + b.z) + c.z) / 3.0f; df = zq - zz; st.z = zz + df; lsum = fmaf(df, df, lsum);
            zq = ((a.w + b.w) + c.w) / 3.0f; df = zq - zw; st.w = zw + df; lsum = fmaf(df, df, lsum);
            o4[k4] = st;                                    // out0 write-once
        }

        size_t ob = (size_t)row * 3;
        out4[ob]     = (float)j0;
        out4[ob + 1] = (float)j1;
        out4[ob + 2] = (float)j2;
        atomicAdd(&hist[j0], 1);
        atomicAdd(&hist[j1], 1);
        atomicAdd(&hist[j2], 1);

        // wave-level reduce of loss partial, one atomic per wave
#pragma unroll
        for (int off = 32; off >= 1; off >>= 1) lsum += __shfl_down(lsum, off);
        if ((t & 63) == 0) atomicAdd(lossAcc, lsum);
    }
}

// ---------------------------------------------------------------------------
// Perplexity from histogram + loss finalize (unchanged).
// ---------------------------------------------------------------------------
__global__ __launch_bounds__(256) void finalize_kernel(const int* __restrict__ hist,
                                                       const float* __restrict__ lossAcc,
                                                       float* __restrict__ out1,
                                                       float* __restrict__ out2) {
    __shared__ float red[256];
    int t = threadIdx.x;
    float local = 0.0f;
    for (int b = t; b < CB; b += 256) {
        float em = (float)hist[b] / 196608.0f;
        local += em * logf(em + 1e-10f);
    }
    red[t] = local;
    __syncthreads();
    for (int s = 128; s >= 1; s >>= 1) {
        if (t < s) red[t] += red[t + s];
        __syncthreads();
    }
    if (t == 0) {
        *out2 = expf(-red[0]);
        float m = *lossAcc / 4194304.0f;
        *out1 = 0.25f * m + m;     // BETA_C*mse + mse
    }
}

extern "C" void kernel_launch(void* const* d_in, const int* in_sizes, int n_in,
                              void* d_out, int out_size, void* d_ws, size_t ws_size,
                              hipStream_t stream) {
    const float* z   = (const float*)d_in[0];   // [16,64,64,64] -> 65536 x 64
    const float* emb = (const float*)d_in[1];   // [1024, 64]

    float* out  = (float*)d_out;
    float* out0 = out;                                    // z_q_st  4194304
    float* out1 = out + 4194304;                          // loss    1
    float* out2 = out + 4194305;                          // perplexity 1
    float* out3 = out + 4194306;                          // encodings 201326592
    float* out4 = out + 4194306 + 201326592ll;            // topk_idx (as float) 196608

    int*   hist    = (int*)d_ws;                          // 1024 ints @ 0
    float* lossAcc = (float*)((char*)d_ws + 4096);        // 1 float
    float* B       = (float*)((char*)d_ws + 8192);        // 1024 floats

    prep_kernel<<<4, 256, 0, stream>>>(emb, B, hist, lossAcc);
    fused_kernel<<<N_ROWS / 64, 256, 0, stream>>>(z, emb, B, out0, out3, out4,
                                                  hist, lossAcc);
    finalize_kernel<<<1, 256, 0, stream>>>(hist, lossAcc, out1, out2);
}